// Round 2
// baseline (2509.342 us; speedup 1.0000x reference)
//
#include <hip/hip_runtime.h>

#define Bg    32
#define NNg   513
#define INF   128
#define OUTF  256
#define TT    4
#define NSTEP 4
#define DEGg  16
#define Ntot  (Bg*NNg)        // 16416
#define Etot  (Ntot*DEGg)     // 262656
#define CATF  (OUTF+INF)      // 384

// ---------------- elementwise ----------------
__global__ void pad_h_k(const float* __restrict__ feat, float* __restrict__ h) {
  int idx = blockIdx.x*256 + threadIdx.x;
  if (idx >= Ntot*OUTF) return;
  int n = idx >> 8, c = idx & 255;
  h[idx] = (c < INF) ? feat[n*INF + c] : 0.f;
}

__global__ void build_cb_k(const float* __restrict__ h, const float* __restrict__ feat,
                           float* __restrict__ cb) {
  int idx = blockIdx.x*256 + threadIdx.x;
  if (idx >= Ntot*CATF) return;
  int n = idx / CATF, c = idx % CATF;
  cb[idx] = (c < OUTF) ? h[n*OUTF + c] : feat[n*INF + (c - OUTF)];
}

__global__ void zero_int_k(int* __restrict__ p, int n) {
  int i = blockIdx.x*256 + threadIdx.x;
  if (i < n) p[i] = 0;
}

__global__ void hist_k(const int* __restrict__ dst, int* __restrict__ cnt) {
  int e = blockIdx.x*256 + threadIdx.x;
  if (e < Etot) atomicAdd(&cnt[dst[e]], 1);
}

__global__ void scan_k(const int* __restrict__ cnt, int* __restrict__ rowptr) {
  __shared__ int buf[256];
  __shared__ int carry_s;
  if (threadIdx.x == 0) carry_s = 0;
  __syncthreads();
  for (int base = 0; base < Ntot; base += 256) {
    int i = base + threadIdx.x;
    int v = (i < Ntot) ? cnt[i] : 0;
    buf[threadIdx.x] = v;
    __syncthreads();
    #pragma unroll
    for (int off = 1; off < 256; off <<= 1) {
      int t = (threadIdx.x >= off) ? buf[threadIdx.x - off] : 0;
      __syncthreads();
      buf[threadIdx.x] += t;
      __syncthreads();
    }
    if (i < Ntot) rowptr[i] = carry_s + buf[threadIdx.x] - v;
    __syncthreads();
    if (threadIdx.x == 255) carry_s += buf[255];
    __syncthreads();
  }
  if (threadIdx.x == 0) rowptr[Ntot] = carry_s;
}

__global__ void fill_k(const int* __restrict__ dst, const int* __restrict__ rowptr,
                       int* __restrict__ cursor, int* __restrict__ eidx) {
  int e = blockIdx.x*256 + threadIdx.x;
  if (e < Etot) {
    int d = dst[e];
    int pos = atomicAdd(&cursor[d], 1);
    eidx[rowptr[d] + pos] = e;
  }
}

// a[n][c] = sum over incoming edges e of HW[src(e)][etype(e)*256 + c]
__global__ void aggregate_k(const float* __restrict__ HW, const int* __restrict__ rowptr,
                            const int* __restrict__ eidx, const int* __restrict__ esrc,
                            const int* __restrict__ etyp, float* __restrict__ a) {
  int n = blockIdx.x;
  int c = threadIdx.x;  // 256
  int s = rowptr[n], epd = rowptr[n+1];
  float acc = 0.f;
  for (int i = s; i < epd; ++i) {
    int e = eidx[i];
    int src = esrc[e];
    int t = etyp[e];
    acc += HW[(size_t)src*1024 + t*256 + c];
  }
  a[(size_t)n*256 + c] = acc;
}

__global__ void gru_gate_k(const float* __restrict__ gi, const float* __restrict__ gh,
                           float* __restrict__ h) {
  int idx = blockIdx.x*256 + threadIdx.x;
  if (idx >= Ntot*OUTF) return;
  int n = idx >> 8, g = idx & 255;
  const float* gin = gi + (size_t)n*768;
  const float* ghn = gh + (size_t)n*768;
  float r  = 1.f / (1.f + expf(-(gin[g]       + ghn[g])));
  float z  = 1.f / (1.f + expf(-(gin[256 + g] + ghn[256 + g])));
  float nn = tanhf(gin[512 + g] + r * ghn[512 + g]);
  float hv = h[idx];
  h[idx] = (1.f - z) * nn + z * hv;
}

__global__ void maxpool_k(const float* __restrict__ in, float* __restrict__ out,
                          int Lin, int Lp, int C, int kwin) {
  int idx = blockIdx.x*256 + threadIdx.x;
  int total = Bg*Lp*C;
  if (idx >= total) return;
  int c = idx % C; int r = idx / C; int p = r % Lp; int b = r / Lp;
  const float* base = in + ((size_t)(b*Lin + 2*p))*C + c;
  float v = base[0];
  for (int w = 1; w < kwin; ++w) v = fmaxf(v, base[(size_t)w*C]);
  out[idx] = v;
}

// wk[co][k][ci] = w[co][ci][k]
__global__ void repack_k(const float* __restrict__ w, float* __restrict__ wk,
                         int Cout, int Cin, int K) {
  int idx = blockIdx.x*256 + threadIdx.x;
  int total = Cout*Cin*K;
  if (idx >= total) return;
  int ci = idx % Cin; int r = idx / Cin; int k = r % K; int co = r / K;
  wk[idx] = w[(co*Cin + ci)*K + k];
}

__global__ void head_k(const float* __restrict__ Y2, const float* __restrict__ Z2,
                       const float* __restrict__ wy, const float* __restrict__ by,
                       const float* __restrict__ wz, const float* __restrict__ bz,
                       float* __restrict__ out) {
  int b = blockIdx.x;
  int tid = threadIdx.x;  // 128
  __shared__ float red[128];
  float sum = 0.f;
  for (int p = tid; p < 127; p += 128) {
    const float* yr = Y2 + ((size_t)(b*127 + p))*OUTF;
    const float* zr = Z2 + ((size_t)(b*127 + p))*CATF;
    float yv = by[0], zv = bz[0];
    for (int c = 0; c < OUTF; ++c) yv = fmaf(yr[c], wy[c], yv);
    for (int c = 0; c < CATF; ++c) zv = fmaf(zr[c], wz[c], zv);
    sum += yv * zv;
  }
  red[tid] = sum;
  __syncthreads();
  for (int off = 64; off > 0; off >>= 1) {
    if (tid < off) red[tid] += red[tid + off];
    __syncthreads();
  }
  if (tid == 0) out[b] = 1.f / (1.f + expf(-red[0] / 127.f));
}

// ---------------- GEMM: C[m][n] = act( sum_k A[m][k]*W[n][k] + bias[n] ) ----------------
// A row m starts at A + node(m)*arstride and is K contiguous floats.
// MAPPED: node(m) = (m/Lout)*NNodes + (m%Lout)   (conv-as-GEMM row mapping)
template<bool RELU, bool MAPPED>
__global__ __launch_bounds__(256) void gemm_tn(
    const float* __restrict__ A, const float* __restrict__ W,
    const float* __restrict__ bias, float* __restrict__ C,
    int M, int Nout, int K, int arstride, int Lout, int NNodes) {
  __shared__ __align__(16) float As[16][68];
  __shared__ __align__(16) float Ws[16][68];
  int tid = threadIdx.x;
  int tx = tid & 15, ty = tid >> 4;
  int m0 = blockIdx.x * 64, n0 = blockIdx.y * 64;
  int kk = tx;
  const float* arow[4];
  const float* wrow[4];
  bool av[4];
  #pragma unroll
  for (int i = 0; i < 4; ++i) {
    int mm = ty + i*16;
    int m = m0 + mm;
    av[i] = (m < M);
    int mc = av[i] ? m : 0;
    int node = MAPPED ? (mc / Lout) * NNodes + (mc % Lout) : mc;
    arow[i] = A + (size_t)node * arstride + kk;
    wrow[i] = W + (size_t)(n0 + mm) * K + kk;
  }
  float c[4][4] = {};
  for (int k0 = 0; k0 < K; k0 += 16) {
    #pragma unroll
    for (int i = 0; i < 4; ++i) {
      int mm = ty + i*16;
      As[kk][mm] = av[i] ? arow[i][k0] : 0.f;
      Ws[kk][mm] = wrow[i][k0];
    }
    __syncthreads();
    #pragma unroll
    for (int k = 0; k < 16; ++k) {
      float4 ra = *reinterpret_cast<const float4*>(&As[k][ty*4]);
      float4 rb = *reinterpret_cast<const float4*>(&Ws[k][tx*4]);
      float rav[4] = {ra.x, ra.y, ra.z, ra.w};
      float rbv[4] = {rb.x, rb.y, rb.z, rb.w};
      #pragma unroll
      for (int ii = 0; ii < 4; ++ii)
        #pragma unroll
        for (int jj = 0; jj < 4; ++jj)
          c[ii][jj] = fmaf(rav[ii], rbv[jj], c[ii][jj]);
    }
    __syncthreads();
  }
  float4 bv = *reinterpret_cast<const float4*>(&bias[n0 + tx*4]);
  float bvv[4] = {bv.x, bv.y, bv.z, bv.w};
  #pragma unroll
  for (int i = 0; i < 4; ++i) {
    int m = m0 + ty*4 + i;
    if (m >= M) continue;
    float4 o;
    float ov[4];
    #pragma unroll
    for (int jj = 0; jj < 4; ++jj) {
      float v = c[i][jj] + bvv[jj];
      if (RELU) v = fmaxf(v, 0.f);
      ov[jj] = v;
    }
    o.x = ov[0]; o.y = ov[1]; o.z = ov[2]; o.w = ov[3];
    *reinterpret_cast<float4*>(&C[(size_t)m*Nout + n0 + tx*4]) = o;
  }
}

static inline int cdiv(int x, int y) { return (x + y - 1) / y; }

extern "C" void kernel_launch(void* const* d_in, const int* in_sizes, int n_in,
                              void* d_out, int out_size, void* d_ws, size_t ws_size,
                              hipStream_t stream) {
  const float* feature  = (const float*)d_in[0];
  const float* W_msg    = (const float*)d_in[1];   // [4,256,256] -> [1024,256]
  const float* b_msg    = (const float*)d_in[2];   // [4,256] -> [1024]
  const float* w_ih     = (const float*)d_in[3];
  const float* w_hh     = (const float*)d_in[4];
  const float* b_ih     = (const float*)d_in[5];
  const float* b_hh     = (const float*)d_in[6];
  const float* conv1_w  = (const float*)d_in[7];
  const float* conv1_b  = (const float*)d_in[8];
  const float* conv2_w  = (const float*)d_in[9];   // [256,256,1] usable directly
  const float* conv2_b  = (const float*)d_in[10];
  const float* convc1_w = (const float*)d_in[11];
  const float* convc1_b = (const float*)d_in[12];
  const float* convc2_w = (const float*)d_in[13];
  const float* convc2_b = (const float*)d_in[14];
  const float* mlpy_w   = (const float*)d_in[15];
  const float* mlpy_b   = (const float*)d_in[16];
  const float* mlpz_w   = (const float*)d_in[17];
  const float* mlpz_b   = (const float*)d_in[18];
  const int*   esrc     = (const int*)d_in[19];
  const int*   edst     = (const int*)d_in[20];
  const int*   etyp     = (const int*)d_in[21];
  float* out = (float*)d_out;

  // ---- workspace layout (floats) ----
  float* ws  = (float*)d_ws;
  float* h   = ws;                                   // N*256
  float* a   = h  + (size_t)Ntot*OUTF;               // N*256
  float* big = a  + (size_t)Ntot*OUTF;               // N*1536
  float* HW  = big;                                  // N*1024 (step phase 1)
  float* gi  = big;                                  // N*768  (aliases HW; HW dead by then)
  float* gh  = big + (size_t)Ntot*768;               // N*768
  float* fend = big + (size_t)Ntot*1536;
  int* rowptr = (int*)fend;                          // N+1
  int* cnt    = rowptr + (Ntot + 1);                 // N
  int* eidx   = cnt + Ntot;                          // E
  // conv-stage region aliases [a .. big end) — GGNN scratch is dead there
  float* Y2   = a;                                   // 32*127*256
  float* Z2   = Y2  + (size_t)Bg*127*OUTF;           // 32*127*384
  float* wk1  = Z2  + (size_t)Bg*127*CATF;           // 256*768
  float* wkc1 = wk1 + (size_t)256*768;               // 384*1152
  float* wkc2 = wkc1 + (size_t)384*1152;             // 384*768
  float* P    = wkc2 + (size_t)384*768;
  float* y1 = P;                                     // 32*511*256
  float* p1 = y1 + (size_t)Bg*511*OUTF;              // 32*255*256
  float* y2 = p1 + (size_t)Bg*255*OUTF;              // 32*255*256
  float* cb  = P;                                    // N*384   (Z phase reuses P)
  float* z1  = cb  + (size_t)Ntot*CATF;              // 32*511*384
  float* pz1 = z1  + (size_t)Bg*511*CATF;            // 32*255*384
  float* z2  = pz1 + (size_t)Bg*255*CATF;            // 32*254*384

  dim3 blk(256);

  // 1. h = pad(feature)
  pad_h_k<<<cdiv(Ntot*OUTF,256), blk, 0, stream>>>(feature, h);

  // 2. CSR by dst (once per launch)
  zero_int_k<<<cdiv(Ntot,256), blk, 0, stream>>>(cnt, Ntot);
  hist_k<<<cdiv(Etot,256), blk, 0, stream>>>(edst, cnt);
  scan_k<<<1, blk, 0, stream>>>(cnt, rowptr);
  zero_int_k<<<cdiv(Ntot,256), blk, 0, stream>>>(cnt, Ntot);
  fill_k<<<cdiv(Etot,256), blk, 0, stream>>>(edst, rowptr, cnt, eidx);

  // 3. GGNN steps
  for (int s = 0; s < NSTEP; ++s) {
    gemm_tn<false,false><<<dim3(cdiv(Ntot,64), 16), blk, 0, stream>>>(
        h, W_msg, b_msg, HW, Ntot, 1024, 256, 256, 0, 0);
    aggregate_k<<<Ntot, blk, 0, stream>>>(HW, rowptr, eidx, esrc, etyp, a);
    gemm_tn<false,false><<<dim3(cdiv(Ntot,64), 12), blk, 0, stream>>>(
        a, w_ih, b_ih, gi, Ntot, 768, 256, 256, 0, 0);
    gemm_tn<false,false><<<dim3(cdiv(Ntot,64), 12), blk, 0, stream>>>(
        h, w_hh, b_hh, gh, Ntot, 768, 256, 256, 0, 0);
    gru_gate_k<<<cdiv(Ntot*OUTF,256), blk, 0, stream>>>(gi, gh, h);
  }

  // 4. weight repacks  wk[co][k][ci]
  repack_k<<<cdiv(256*256*3,256), blk, 0, stream>>>(conv1_w,  wk1,  256, 256, 3);
  repack_k<<<cdiv(384*384*3,256), blk, 0, stream>>>(convc1_w, wkc1, 384, 384, 3);
  repack_k<<<cdiv(384*384*2,256), blk, 0, stream>>>(convc2_w, wkc2, 384, 384, 2);

  // 5. Y head: conv1(K=3) -> pool3 -> conv2(K=1) -> pool2
  gemm_tn<true,true><<<dim3(cdiv(Bg*511,64), 4), blk, 0, stream>>>(
      h, wk1, conv1_b, y1, Bg*511, 256, 768, 256, 511, NNg);
  maxpool_k<<<cdiv(Bg*255*256,256), blk, 0, stream>>>(y1, p1, 511, 255, 256, 3);
  gemm_tn<true,false><<<dim3(cdiv(Bg*255,64), 4), blk, 0, stream>>>(
      p1, conv2_w, conv2_b, y2, Bg*255, 256, 256, 256, 0, 0);
  maxpool_k<<<cdiv(Bg*127*256,256), blk, 0, stream>>>(y2, Y2, 255, 127, 256, 2);

  // 6. Z head: cb=concat(h,feature); convc1(K=3) -> pool3 -> convc2(K=2) -> pool2
  build_cb_k<<<cdiv(Ntot*CATF,256), blk, 0, stream>>>(h, feature, cb);
  gemm_tn<true,true><<<dim3(cdiv(Bg*511,64), 6), blk, 0, stream>>>(
      cb, wkc1, convc1_b, z1, Bg*511, 384, 1152, 384, 511, NNg);
  maxpool_k<<<cdiv(Bg*255*384,256), blk, 0, stream>>>(z1, pz1, 511, 255, 384, 3);
  gemm_tn<true,true><<<dim3(cdiv(Bg*254,64), 6), blk, 0, stream>>>(
      pz1, wkc2, convc2_b, z2, Bg*254, 384, 768, 384, 254, 255);
  maxpool_k<<<cdiv(Bg*127*384,256), blk, 0, stream>>>(z2, Z2, 254, 127, 384, 2);

  // 7. head
  head_k<<<Bg, 128, 0, stream>>>(Y2, Z2, mlpy_w, mlpy_b, mlpz_w, mlpz_b, out);
}

// Round 6
// 1221.969 us; speedup vs baseline: 2.0535x; 2.0535x over previous
//
#include <hip/hip_runtime.h>

#define Bg    32
#define NNg   513
#define INF   128
#define OUTF  256
#define TT    4
#define NSTEP 4
#define DEGg  16
#define Ntot  (Bg*NNg)        // 16416
#define Etot  (Ntot*DEGg)     // 262656
#define CATF  (OUTF+INF)      // 384

typedef _Float16 h8_t __attribute__((ext_vector_type(8)));
typedef float    f4_t __attribute__((ext_vector_type(4)));

// ---------------- elementwise ----------------
__global__ void pad_h_k(const float* __restrict__ feat, float* __restrict__ h,
                        _Float16* __restrict__ h16) {
  int idx = blockIdx.x*256 + threadIdx.x;
  if (idx >= Ntot*OUTF) return;
  int n = idx >> 8, c = idx & 255;
  float v = (c < INF) ? feat[n*INF + c] : 0.f;
  h[idx] = v;
  h16[idx] = (_Float16)v;
}

__global__ void cvt_k(const float* __restrict__ s, _Float16* __restrict__ d, int n) {
  int i = (blockIdx.x*256 + threadIdx.x) * 4;
  if (i >= n) return;
  float4 v = *reinterpret_cast<const float4*>(s + i);
  _Float16 o[4] = {(_Float16)v.x, (_Float16)v.y, (_Float16)v.z, (_Float16)v.w};
  *reinterpret_cast<ushort4*>(d + i) = *reinterpret_cast<ushort4*>(o);
}

// cb16[n][c] = c<256 ? h16[n][c] : (f16)feature[n][c-256]
__global__ void build_cb16_k(const _Float16* __restrict__ h16,
                             const float* __restrict__ feat,
                             _Float16* __restrict__ cb) {
  int idx = blockIdx.x*256 + threadIdx.x;
  if (idx >= Ntot*CATF) return;
  int n = idx / CATF, c = idx % CATF;
  cb[idx] = (c < OUTF) ? h16[n*OUTF + c] : (_Float16)feat[n*INF + (c - OUTF)];
}

__global__ void zero_int_k(int* __restrict__ p, int n) {
  int i = blockIdx.x*256 + threadIdx.x;
  if (i < n) p[i] = 0;
}

__global__ void hist_k(const int* __restrict__ dst, int* __restrict__ cnt) {
  int e = blockIdx.x*256 + threadIdx.x;
  if (e < Etot) atomicAdd(&cnt[dst[e]], 1);
}

__global__ void scan_k(const int* __restrict__ cnt, int* __restrict__ rowptr) {
  __shared__ int buf[256];
  __shared__ int carry_s;
  if (threadIdx.x == 0) carry_s = 0;
  __syncthreads();
  for (int base = 0; base < Ntot; base += 256) {
    int i = base + threadIdx.x;
    int v = (i < Ntot) ? cnt[i] : 0;
    buf[threadIdx.x] = v;
    __syncthreads();
    #pragma unroll
    for (int off = 1; off < 256; off <<= 1) {
      int t = (threadIdx.x >= off) ? buf[threadIdx.x - off] : 0;
      __syncthreads();
      buf[threadIdx.x] += t;
      __syncthreads();
    }
    if (i < Ntot) rowptr[i] = carry_s + buf[threadIdx.x] - v;
    __syncthreads();
    if (threadIdx.x == 255) carry_s += buf[255];
    __syncthreads();
  }
  if (threadIdx.x == 0) rowptr[Ntot] = carry_s;
}

__global__ void fill_k(const int* __restrict__ dst, const int* __restrict__ rowptr,
                       int* __restrict__ cursor, int* __restrict__ eidx) {
  int e = blockIdx.x*256 + threadIdx.x;
  if (e < Etot) {
    int d = dst[e];
    int pos = atomicAdd(&cursor[d], 1);
    eidx[rowptr[d] + pos] = e;
  }
}

// a16[n][c] = (f16) sum over incoming edges e of HW[src(e)][etype(e)*256 + c]
__global__ void aggregate_k(const float* __restrict__ HW, const int* __restrict__ rowptr,
                            const int* __restrict__ eidx, const int* __restrict__ esrc,
                            const int* __restrict__ etyp, _Float16* __restrict__ a16) {
  int n = blockIdx.x;
  int c = threadIdx.x;  // 256
  int s = rowptr[n], epd = rowptr[n+1];
  float acc = 0.f;
  for (int i = s; i < epd; ++i) {
    int e = eidx[i];
    int src = esrc[e];
    int t = etyp[e];
    acc += HW[(size_t)src*1024 + t*256 + c];
  }
  a16[(size_t)n*256 + c] = (_Float16)acc;
}

__global__ void gru_gate_k(const float* __restrict__ gi, const float* __restrict__ gh,
                           float* __restrict__ h, _Float16* __restrict__ h16) {
  int idx = blockIdx.x*256 + threadIdx.x;
  if (idx >= Ntot*OUTF) return;
  int n = idx >> 8, g = idx & 255;
  const float* gin = gi + (size_t)n*768;
  const float* ghn = gh + (size_t)n*768;
  float r  = 1.f / (1.f + expf(-(gin[g]       + ghn[g])));
  float z  = 1.f / (1.f + expf(-(gin[256 + g] + ghn[256 + g])));
  float nn = tanhf(gin[512 + g] + r * ghn[512 + g]);
  float hv = h[idx];
  float o = (1.f - z) * nn + z * hv;
  h[idx] = o;
  h16[idx] = (_Float16)o;
}

template<typename OT>
__global__ void maxpool_k(const float* __restrict__ in, OT* __restrict__ out,
                          int Lin, int Lp, int C, int kwin) {
  int idx = blockIdx.x*256 + threadIdx.x;
  int total = Bg*Lp*C;
  if (idx >= total) return;
  int c = idx % C; int r = idx / C; int p = r % Lp; int b = r / Lp;
  const float* base = in + ((size_t)(b*Lin + 2*p))*C + c;
  float v = base[0];
  for (int w = 1; w < kwin; ++w) v = fmaxf(v, base[(size_t)w*C]);
  out[idx] = (OT)v;
}

// wk16[co][k][ci] = (f16) w[co][ci][k]
__global__ void repack16_k(const float* __restrict__ w, _Float16* __restrict__ wk,
                           int Cout, int Cin, int K) {
  int idx = blockIdx.x*256 + threadIdx.x;
  int total = Cout*Cin*K;
  if (idx >= total) return;
  int ci = idx % Cin; int r = idx / Cin; int k = r % K; int co = r / K;
  wk[idx] = (_Float16)w[(co*Cin + ci)*K + k];
}

__global__ void head_k(const float* __restrict__ Y2, const float* __restrict__ Z2,
                       const float* __restrict__ wy, const float* __restrict__ by,
                       const float* __restrict__ wz, const float* __restrict__ bz,
                       float* __restrict__ out) {
  int b = blockIdx.x;
  int tid = threadIdx.x;  // 128
  __shared__ float red[128];
  float sum = 0.f;
  for (int p = tid; p < 127; p += 128) {
    const float* yr = Y2 + ((size_t)(b*127 + p))*OUTF;
    const float* zr = Z2 + ((size_t)(b*127 + p))*CATF;
    float yv = by[0], zv = bz[0];
    for (int c = 0; c < OUTF; ++c) yv = fmaf(yr[c], wy[c], yv);
    for (int c = 0; c < CATF; ++c) zv = fmaf(zr[c], wz[c], zv);
    sum += yv * zv;
  }
  red[tid] = sum;
  __syncthreads();
  for (int off = 64; off > 0; off >>= 1) {
    if (tid < off) red[tid] += red[tid + off];
    __syncthreads();
  }
  if (tid == 0) out[b] = 1.f / (1.f + expf(-red[0] / 127.f));
}

// ------------- f16 MFMA GEMM: C[m][n] = act(sum_k A[m][k]*W[n][k] + bias[n]) -------------
// Tile 128x64xK, BK=32, 256 threads = 4 waves (2x2), wave tile 64x32 = 4x2 MFMA frags.
// A row m at A + node(m)*arstride (f16 elems), K contiguous.
// MAPPED: node(m) = (m/Lout)*NNodes + (m%Lout)   (conv-as-GEMM row mapping)
template<bool RELU, bool MAPPED>
__global__ __launch_bounds__(256, 2) void hgemm(
    const _Float16* __restrict__ A, const _Float16* __restrict__ W,
    const float* __restrict__ bias, float* __restrict__ C,
    int M, int Nout, int K, int arstride, int Lout, int NNodes) {
  __shared__ _Float16 As[128][40];   // padded: 80B row stride -> conflict-free b128 reads
  __shared__ _Float16 Ws[64][40];
  int tid = threadIdx.x;
  int lane = tid & 63, wid = tid >> 6;
  int wm = wid >> 1, wn = wid & 1;
  int l15 = lane & 15, l4 = lane >> 4;
  int m0 = blockIdx.x * 128, n0 = blockIdx.y * 64;

  // staging: A 128 rows x 32 f16, 2 threads/row x 16 f16 (2x16B)
  int sa_row = tid >> 1;
  int sa_col = (tid & 1) * 16;
  int m_s = m0 + sa_row;
  bool a_ok = (m_s < M);
  int mc = a_ok ? m_s : (M - 1);
  int node = MAPPED ? (mc / Lout) * NNodes + (mc % Lout) : mc;
  const _Float16* a_src = A + (size_t)node * arstride + sa_col;
  // staging: W 64 rows x 32 f16, 4 threads/row x 8 f16 (16B)
  int sw_row = tid >> 2;
  int sw_col = (tid & 3) * 8;
  const _Float16* w_src = W + (size_t)(n0 + sw_row) * K + sw_col;

  f4_t acc[4][2] = {};

  for (int k0 = 0; k0 < K; k0 += 32) {
    if (k0) __syncthreads();
    int4 v0 = {0,0,0,0}, v1 = {0,0,0,0};
    if (a_ok) {
      const int4* g = reinterpret_cast<const int4*>(a_src + k0);
      v0 = g[0]; v1 = g[1];
    }
    *reinterpret_cast<int4*>(&As[sa_row][sa_col])     = v0;
    *reinterpret_cast<int4*>(&As[sa_row][sa_col + 8]) = v1;
    *reinterpret_cast<int4*>(&Ws[sw_row][sw_col]) =
        *reinterpret_cast<const int4*>(w_src + k0);
    __syncthreads();

    h8_t af[4], bf[2];
    #pragma unroll
    for (int fm = 0; fm < 4; ++fm)
      af[fm] = *reinterpret_cast<const h8_t*>(&As[wm*64 + fm*16 + l15][l4*8]);
    #pragma unroll
    for (int fn = 0; fn < 2; ++fn)
      bf[fn] = *reinterpret_cast<const h8_t*>(&Ws[wn*32 + fn*16 + l15][l4*8]);
    #pragma unroll
    for (int fm = 0; fm < 4; ++fm)
      #pragma unroll
      for (int fn = 0; fn < 2; ++fn)
        acc[fm][fn] = __builtin_amdgcn_mfma_f32_16x16x32_f16(af[fm], bf[fn], acc[fm][fn], 0, 0, 0);
  }

  // epilogue: D row = (lane>>4)*4 + reg, col = lane&15  (verified C/D layout)
  #pragma unroll
  for (int fn = 0; fn < 2; ++fn) {
    int col = n0 + wn*32 + fn*16 + l15;
    float bv = bias[col];
    #pragma unroll
    for (int fm = 0; fm < 4; ++fm) {
      #pragma unroll
      for (int i = 0; i < 4; ++i) {
        int m = m0 + wm*64 + fm*16 + l4*4 + i;
        if (m >= M) continue;
        float v = acc[fm][fn][i] + bv;
        if (RELU) v = fmaxf(v, 0.f);
        C[(size_t)m * Nout + col] = v;
      }
    }
  }
}

static inline int cdiv(int x, int y) { return (x + y - 1) / y; }

extern "C" void kernel_launch(void* const* d_in, const int* in_sizes, int n_in,
                              void* d_out, int out_size, void* d_ws, size_t ws_size,
                              hipStream_t stream) {
  const float* feature  = (const float*)d_in[0];
  const float* W_msg    = (const float*)d_in[1];   // [4,256,256] -> [1024,256]
  const float* b_msg    = (const float*)d_in[2];   // [1024]
  const float* w_ih     = (const float*)d_in[3];
  const float* w_hh     = (const float*)d_in[4];
  const float* b_ih     = (const float*)d_in[5];
  const float* b_hh     = (const float*)d_in[6];
  const float* conv1_w  = (const float*)d_in[7];
  const float* conv1_b  = (const float*)d_in[8];
  const float* conv2_w  = (const float*)d_in[9];   // [256,256,1]
  const float* conv2_b  = (const float*)d_in[10];
  const float* convc1_w = (const float*)d_in[11];
  const float* convc1_b = (const float*)d_in[12];
  const float* convc2_w = (const float*)d_in[13];
  const float* convc2_b = (const float*)d_in[14];
  const float* mlpy_w   = (const float*)d_in[15];
  const float* mlpy_b   = (const float*)d_in[16];
  const float* mlpz_w   = (const float*)d_in[17];
  const float* mlpz_b   = (const float*)d_in[18];
  const int*   esrc     = (const int*)d_in[19];
  const int*   edst     = (const int*)d_in[20];
  const int*   etyp     = (const int*)d_in[21];
  float* out = (float*)d_out;

  // ---- workspace layout (bytes); peak ~128.6 MB (< round-2-verified ~136 MB) ----
  char* base = (char*)d_ws;
  size_t off = 0;
  auto alloc = [&](size_t bytes) { void* p = base + off; off = (off + bytes + 255) & ~(size_t)255; return p; };
  float*    h      = (float*)   alloc((size_t)Ntot*OUTF*4);    // 16.8 MB
  _Float16* h16    = (_Float16*)alloc((size_t)Ntot*OUTF*2);    //  8.4 MB
  _Float16* Wmsg16 = (_Float16*)alloc((size_t)1024*256*2);
  _Float16* wih16  = (_Float16*)alloc((size_t)768*256*2);
  _Float16* whh16  = (_Float16*)alloc((size_t)768*256*2);
  int* rowptr = (int*)alloc((Ntot+1)*4);
  int* cnt    = (int*)alloc(Ntot*4);
  int* eidx   = (int*)alloc((size_t)Etot*4);
  char* big   = (char*)alloc((size_t)Ntot*1536*4);             // 100.9 MB shared region
  // GGNN phase views of big:
  //   HW  = big[0 : 67.2MB)            (f32, N*1024)
  //   a16 = big[67.2 : 75.6MB)         (f16, N*256) — written by aggregate while HW live
  //         (disjoint); consumed by gi-GEMM BEFORE gh-GEMM overwrites [50.4:100.9MB)
  //   gi  = big[0 : 50.4MB)            (f32, N*768; HW dead by then)
  //   gh  = big[50.4 : 100.9MB)        (f32, N*768)
  float*    HW  = (float*)big;
  _Float16* a16 = (_Float16*)(big + (size_t)Ntot*1024*4);
  float*    gi  = (float*)big;
  float*    gh  = gi + (size_t)Ntot*768;
  // conv phase views of big (GGNN scratch dead; 96.2MB data + 2.0MB weights <= 100.9MB)
  float*    Y2   = (float*)big;                              // 32*127*256 f32
  float*    Z2   = Y2 + (size_t)Bg*127*OUTF;                 // 32*127*384 f32
  float*    y1   = Z2 + (size_t)Bg*127*CATF;                 // 32*511*256 f32
  float*    y2   = y1 + (size_t)Bg*511*OUTF;                 // 32*255*256 f32
  _Float16* p1   = (_Float16*)(y2 + (size_t)Bg*255*OUTF);    // 32*255*256 f16
  _Float16* cb16 = p1 + (size_t)Bg*255*OUTF;                 // 16416*384 f16
  float*    z1   = (float*)(cb16 + (size_t)Ntot*CATF);       // 32*511*384 f32
  float*    z2   = z1 + (size_t)Bg*511*CATF;                 // 32*254*384 f32
  _Float16* pz1  = (_Float16*)(z2 + (size_t)Bg*254*CATF);    // 32*255*384 f16
  _Float16* wk1  = pz1 + (size_t)Bg*255*CATF;                // 256*768  f16 (conv-phase only)
  _Float16* wkc1 = wk1 + (size_t)256*768;                    // 384*1152 f16
  _Float16* wkc2 = wkc1 + (size_t)384*1152;                  // 384*768  f16
  _Float16* c2w16= wkc2 + (size_t)384*768;                   // 256*256  f16

  dim3 blk(256);

  // 1. h = pad(feature) (f32 + f16); GGNN weight conversions
  pad_h_k<<<cdiv(Ntot*OUTF,256), blk, 0, stream>>>(feature, h, h16);
  cvt_k<<<cdiv(1024*256/4,256), blk, 0, stream>>>(W_msg, Wmsg16, 1024*256);
  cvt_k<<<cdiv(768*256/4,256), blk, 0, stream>>>(w_ih, wih16, 768*256);
  cvt_k<<<cdiv(768*256/4,256), blk, 0, stream>>>(w_hh, whh16, 768*256);

  // 2. CSR by dst
  zero_int_k<<<cdiv(Ntot,256), blk, 0, stream>>>(cnt, Ntot);
  hist_k<<<cdiv(Etot,256), blk, 0, stream>>>(edst, cnt);
  scan_k<<<1, blk, 0, stream>>>(cnt, rowptr);
  zero_int_k<<<cdiv(Ntot,256), blk, 0, stream>>>(cnt, Ntot);
  fill_k<<<cdiv(Etot,256), blk, 0, stream>>>(edst, rowptr, cnt, eidx);

  // 3. GGNN steps
  for (int s = 0; s < NSTEP; ++s) {
    hgemm<false,false><<<dim3(cdiv(Ntot,128), 16), blk, 0, stream>>>(
        h16, Wmsg16, b_msg, HW, Ntot, 1024, 256, 256, 0, 0);
    aggregate_k<<<Ntot, blk, 0, stream>>>(HW, rowptr, eidx, esrc, etyp, a16);
    hgemm<false,false><<<dim3(cdiv(Ntot,128), 12), blk, 0, stream>>>(
        a16, wih16, b_ih, gi, Ntot, 768, 256, 256, 0, 0);
    hgemm<false,false><<<dim3(cdiv(Ntot,128), 12), blk, 0, stream>>>(
        h16, whh16, b_hh, gh, Ntot, 768, 256, 256, 0, 0);
    gru_gate_k<<<cdiv(Ntot*OUTF,256), blk, 0, stream>>>(gi, gh, h, h16);
  }

  // 4. conv-head weight repacks (after GGNN: they live in big's conv-phase spare)
  repack16_k<<<cdiv(256*256*3,256), blk, 0, stream>>>(conv1_w,  wk1,  256, 256, 3);
  repack16_k<<<cdiv(384*384*3,256), blk, 0, stream>>>(convc1_w, wkc1, 384, 384, 3);
  repack16_k<<<cdiv(384*384*2,256), blk, 0, stream>>>(convc2_w, wkc2, 384, 384, 2);
  cvt_k<<<cdiv(256*256/4,256), blk, 0, stream>>>(conv2_w, c2w16, 256*256);

  // 5. Y head: conv1(K=3) -> pool3 -> conv2(K=1) -> pool2
  hgemm<true,true><<<dim3(cdiv(Bg*511,128), 4), blk, 0, stream>>>(
      h16, wk1, conv1_b, y1, Bg*511, 256, 768, 256, 511, NNg);
  maxpool_k<_Float16><<<cdiv(Bg*255*256,256), blk, 0, stream>>>(y1, p1, 511, 255, 256, 3);
  hgemm<true,false><<<dim3(cdiv(Bg*255,128), 4), blk, 0, stream>>>(
      p1, c2w16, conv2_b, y2, Bg*255, 256, 256, 256, 0, 0);
  maxpool_k<float><<<cdiv(Bg*127*256,256), blk, 0, stream>>>(y2, Y2, 255, 127, 256, 2);

  // 6. Z head: cb16=concat(h16,(f16)feature); convc1(K=3) -> pool3 -> convc2(K=2) -> pool2
  build_cb16_k<<<cdiv(Ntot*CATF,256), blk, 0, stream>>>(h16, feature, cb16);
  hgemm<true,true><<<dim3(cdiv(Bg*511,128), 6), blk, 0, stream>>>(
      cb16, wkc1, convc1_b, z1, Bg*511, 384, 1152, 384, 511, NNg);
  maxpool_k<_Float16><<<cdiv(Bg*255*384,256), blk, 0, stream>>>(z1, pz1, 511, 255, 384, 3);
  hgemm<true,true><<<dim3(cdiv(Bg*254,128), 6), blk, 0, stream>>>(
      pz1, wkc2, convc2_b, z2, Bg*254, 384, 768, 384, 254, 255);
  maxpool_k<float><<<cdiv(Bg*127*384,256), blk, 0, stream>>>(z2, Z2, 254, 127, 384, 2);

  // 7. head
  head_k<<<Bg, 128, 0, stream>>>(Y2, Z2, mlpy_w, mlpy_b, mlpz_w, mlpz_b, out);
}

// Round 9
// 972.566 us; speedup vs baseline: 2.5801x; 1.2564x over previous
//
#include <hip/hip_runtime.h>

#define Bg    32
#define NNg   513
#define INF   128
#define OUTF  256
#define TT    4
#define NSTEP 4
#define DEGg  16
#define Ntot  (Bg*NNg)        // 16416
#define Etot  (Ntot*DEGg)     // 262656
#define CATF  (OUTF+INF)      // 384
#define SK    1056            // 1024 + 4 cnt + 28 pad

typedef _Float16 h8_t __attribute__((ext_vector_type(8)));
typedef float    f4_t __attribute__((ext_vector_type(4)));

// ---------------- elementwise ----------------
__global__ void pad_h_k(const float* __restrict__ feat, float* __restrict__ h,
                        _Float16* __restrict__ h16) {
  int idx = blockIdx.x*256 + threadIdx.x;
  if (idx >= Ntot*OUTF) return;
  int n = idx >> 8, c = idx & 255;
  float v = (c < INF) ? feat[n*INF + c] : 0.f;
  h[idx] = v;
  h16[idx] = (_Float16)v;
}

__global__ void cvt_k(const float* __restrict__ s, _Float16* __restrict__ d, int n) {
  int i = (blockIdx.x*256 + threadIdx.x) * 4;
  if (i >= n) return;
  float4 v = *reinterpret_cast<const float4*>(s + i);
  _Float16 o[4] = {(_Float16)v.x, (_Float16)v.y, (_Float16)v.z, (_Float16)v.w};
  *reinterpret_cast<ushort4*>(d + i) = *reinterpret_cast<ushort4*>(o);
}

// cb16[n][c] = c<256 ? h16[n][c] : (f16)feature[n][c-256]
__global__ void build_cb16_k(const _Float16* __restrict__ h16,
                             const float* __restrict__ feat,
                             _Float16* __restrict__ cb) {
  int idx = blockIdx.x*256 + threadIdx.x;
  if (idx >= Ntot*CATF) return;
  int n = idx / CATF, c = idx % CATF;
  cb[idx] = (c < OUTF) ? h16[n*OUTF + c] : (_Float16)feat[n*INF + (c - OUTF)];
}

__global__ void zero_int_k(int* __restrict__ p, int n) {
  int i = blockIdx.x*256 + threadIdx.x;
  if (i < n) p[i] = 0;
}

__global__ void hist_k(const int* __restrict__ dst, int* __restrict__ cnt) {
  int e = blockIdx.x*256 + threadIdx.x;
  if (e < Etot) atomicAdd(&cnt[dst[e]], 1);
}

__global__ void scan_k(const int* __restrict__ cnt, int* __restrict__ rowptr) {
  __shared__ int buf[256];
  __shared__ int carry_s;
  if (threadIdx.x == 0) carry_s = 0;
  __syncthreads();
  for (int base = 0; base < Ntot; base += 256) {
    int i = base + threadIdx.x;
    int v = (i < Ntot) ? cnt[i] : 0;
    buf[threadIdx.x] = v;
    __syncthreads();
    #pragma unroll
    for (int off = 1; off < 256; off <<= 1) {
      int t = (threadIdx.x >= off) ? buf[threadIdx.x - off] : 0;
      __syncthreads();
      buf[threadIdx.x] += t;
      __syncthreads();
    }
    if (i < Ntot) rowptr[i] = carry_s + buf[threadIdx.x] - v;
    __syncthreads();
    if (threadIdx.x == 255) carry_s += buf[255];
    __syncthreads();
  }
  if (threadIdx.x == 0) rowptr[Ntot] = carry_s;
}

__global__ void fill_k(const int* __restrict__ dst, const int* __restrict__ rowptr,
                       int* __restrict__ cursor, int* __restrict__ eidx) {
  int e = blockIdx.x*256 + threadIdx.x;
  if (e < Etot) {
    int d = dst[e];
    int pos = atomicAdd(&cursor[d], 1);
    eidx[rowptr[d] + pos] = e;
  }
}

// Per-type neighbor sums: s16[n][t*256+c] = sum_{e: dst=n, type=t} h16[src(e)][c]
// plus s16[n][1024+t] = count of type-t in-edges (for exact b_msg handling), pad zeros.
__global__ void gather_k(const _Float16* __restrict__ h16, const int* __restrict__ rowptr,
                         const int* __restrict__ eidx, const int* __restrict__ esrc,
                         const int* __restrict__ etyp, _Float16* __restrict__ s16) {
  __shared__ int src_s[128];
  __shared__ int typ_s[128];
  int n = blockIdx.x;
  int c = threadIdx.x;  // 256
  int s0 = rowptr[n], e0 = rowptr[n+1];
  float a0 = 0.f, a1 = 0.f, a2 = 0.f, a3 = 0.f;
  int c0 = 0, c1 = 0, c2 = 0, c3 = 0;
  for (int base = s0; base < e0; base += 128) {
    int m = e0 - base; if (m > 128) m = 128;
    if (c < m) {
      int ee = eidx[base + c];
      src_s[c] = esrc[ee];
      typ_s[c] = etyp[ee];
    }
    __syncthreads();
    for (int i = 0; i < m; ++i) {
      int t = typ_s[i];
      float v = (float)h16[(size_t)src_s[i]*256 + c];
      a0 += (t == 0) ? v : 0.f;
      a1 += (t == 1) ? v : 0.f;
      a2 += (t == 2) ? v : 0.f;
      a3 += (t == 3) ? v : 0.f;
      c0 += (t == 0); c1 += (t == 1); c2 += (t == 2); c3 += (t == 3);
    }
    __syncthreads();
  }
  size_t b = (size_t)n * SK;
  s16[b + 0*256 + c] = (_Float16)a0;
  s16[b + 1*256 + c] = (_Float16)a1;
  s16[b + 2*256 + c] = (_Float16)a2;
  s16[b + 3*256 + c] = (_Float16)a3;
  if (c < 32) {
    float cv = (c == 0) ? (float)c0 : (c == 1) ? (float)c1 :
               (c == 2) ? (float)c2 : (c == 3) ? (float)c3 : 0.f;
    s16[b + 1024 + c] = (_Float16)cv;
  }
}

// Wext[co][k]: k<1024 -> W_msg[k>>8][co][k&255]; k in [1024,1028) -> b_msg[(k-1024)*256+co]; else 0
__global__ void repack_wext_k(const float* __restrict__ Wmsg, const float* __restrict__ bmsg,
                              _Float16* __restrict__ wext) {
  int idx = blockIdx.x*256 + threadIdx.x;
  if (idx >= 256*SK) return;
  int co = idx / SK, k = idx % SK;
  float v;
  if (k < 1024)      { int t = k >> 8, ci = k & 255; v = Wmsg[((size_t)t*256 + co)*256 + ci]; }
  else if (k < 1028) { v = bmsg[(k - 1024)*256 + co]; }
  else               { v = 0.f; }
  wext[idx] = (_Float16)v;
}

__global__ void gru_gate_k(const float* __restrict__ gi, const float* __restrict__ gh,
                           float* __restrict__ h, _Float16* __restrict__ h16) {
  int idx = blockIdx.x*256 + threadIdx.x;
  if (idx >= Ntot*OUTF) return;
  int n = idx >> 8, g = idx & 255;
  const float* gin = gi + (size_t)n*768;
  const float* ghn = gh + (size_t)n*768;
  float r  = 1.f / (1.f + expf(-(gin[g]       + ghn[g])));
  float z  = 1.f / (1.f + expf(-(gin[256 + g] + ghn[256 + g])));
  float nn = tanhf(gin[512 + g] + r * ghn[512 + g]);
  float hv = h[idx];
  float o = (1.f - z) * nn + z * hv;
  h[idx] = o;
  h16[idx] = (_Float16)o;
}

template<typename OT>
__global__ void maxpool_k(const float* __restrict__ in, OT* __restrict__ out,
                          int Lin, int Lp, int C, int kwin) {
  int idx = blockIdx.x*256 + threadIdx.x;
  int total = Bg*Lp*C;
  if (idx >= total) return;
  int c = idx % C; int r = idx / C; int p = r % Lp; int b = r / Lp;
  const float* base = in + ((size_t)(b*Lin + 2*p))*C + c;
  float v = base[0];
  for (int w = 1; w < kwin; ++w) v = fmaxf(v, base[(size_t)w*C]);
  out[idx] = (OT)v;
}

// wk16[co][k][ci] = (f16) w[co][ci][k]
__global__ void repack16_k(const float* __restrict__ w, _Float16* __restrict__ wk,
                           int Cout, int Cin, int K) {
  int idx = blockIdx.x*256 + threadIdx.x;
  int total = Cout*Cin*K;
  if (idx >= total) return;
  int ci = idx % Cin; int r = idx / Cin; int k = r % K; int co = r / K;
  wk[idx] = (_Float16)w[(co*Cin + ci)*K + k];
}

__global__ void head_k(const float* __restrict__ Y2, const float* __restrict__ Z2,
                       const float* __restrict__ wy, const float* __restrict__ by,
                       const float* __restrict__ wz, const float* __restrict__ bz,
                       float* __restrict__ out) {
  int b = blockIdx.x;
  int tid = threadIdx.x;  // 128
  __shared__ float red[128];
  float sum = 0.f;
  for (int p = tid; p < 127; p += 128) {
    const float* yr = Y2 + ((size_t)(b*127 + p))*OUTF;
    const float* zr = Z2 + ((size_t)(b*127 + p))*CATF;
    float yv = by[0], zv = bz[0];
    for (int c = 0; c < OUTF; ++c) yv = fmaf(yr[c], wy[c], yv);
    for (int c = 0; c < CATF; ++c) zv = fmaf(zr[c], wz[c], zv);
    sum += yv * zv;
  }
  red[tid] = sum;
  __syncthreads();
  for (int off = 64; off > 0; off >>= 1) {
    if (tid < off) red[tid] += red[tid + off];
    __syncthreads();
  }
  if (tid == 0) out[b] = 1.f / (1.f + expf(-red[0] / 127.f));
}

// ------------- f16 MFMA GEMM: C[m][n] = act(sum_k A[m][k]*W[n][k] + bias[n]) -------------
// Tile 128x64xK, BK=32, 256 threads = 4 waves (2x2), wave tile 64x32 = 4x2 MFMA frags.
// A row m at A + node(m)*arstride (f16 elems), K contiguous. CT = output type (float/f16).
// MAPPED: node(m) = (m/Lout)*NNodes + (m%Lout)   (conv-as-GEMM row mapping)
template<typename CT, bool RELU, bool MAPPED>
__global__ __launch_bounds__(256, 2) void hgemm(
    const _Float16* __restrict__ A, const _Float16* __restrict__ W,
    const float* __restrict__ bias, CT* __restrict__ C,
    int M, int Nout, int K, int arstride, int Lout, int NNodes) {
  __shared__ _Float16 As[128][40];   // padded: 80B row stride -> conflict-free b128 reads
  __shared__ _Float16 Ws[64][40];
  int tid = threadIdx.x;
  int lane = tid & 63, wid = tid >> 6;
  int wm = wid >> 1, wn = wid & 1;
  int l15 = lane & 15, l4 = lane >> 4;
  int m0 = blockIdx.x * 128, n0 = blockIdx.y * 64;

  // staging: A 128 rows x 32 f16, 2 threads/row x 16 f16 (2x16B)
  int sa_row = tid >> 1;
  int sa_col = (tid & 1) * 16;
  int m_s = m0 + sa_row;
  bool a_ok = (m_s < M);
  int mc = a_ok ? m_s : (M - 1);
  int node = MAPPED ? (mc / Lout) * NNodes + (mc % Lout) : mc;
  const _Float16* a_src = A + (size_t)node * arstride + sa_col;
  // staging: W 64 rows x 32 f16, 4 threads/row x 8 f16 (16B)
  int sw_row = tid >> 2;
  int sw_col = (tid & 3) * 8;
  const _Float16* w_src = W + (size_t)(n0 + sw_row) * K + sw_col;

  f4_t acc[4][2] = {};

  for (int k0 = 0; k0 < K; k0 += 32) {
    if (k0) __syncthreads();
    int4 v0 = {0,0,0,0}, v1 = {0,0,0,0};
    if (a_ok) {
      const int4* g = reinterpret_cast<const int4*>(a_src + k0);
      v0 = g[0]; v1 = g[1];
    }
    *reinterpret_cast<int4*>(&As[sa_row][sa_col])     = v0;
    *reinterpret_cast<int4*>(&As[sa_row][sa_col + 8]) = v1;
    *reinterpret_cast<int4*>(&Ws[sw_row][sw_col]) =
        *reinterpret_cast<const int4*>(w_src + k0);
    __syncthreads();

    h8_t af[4], bf[2];
    #pragma unroll
    for (int fm = 0; fm < 4; ++fm)
      af[fm] = *reinterpret_cast<const h8_t*>(&As[wm*64 + fm*16 + l15][l4*8]);
    #pragma unroll
    for (int fn = 0; fn < 2; ++fn)
      bf[fn] = *reinterpret_cast<const h8_t*>(&Ws[wn*32 + fn*16 + l15][l4*8]);
    #pragma unroll
    for (int fm = 0; fm < 4; ++fm)
      #pragma unroll
      for (int fn = 0; fn < 2; ++fn)
        acc[fm][fn] = __builtin_amdgcn_mfma_f32_16x16x32_f16(af[fm], bf[fn], acc[fm][fn], 0, 0, 0);
  }

  // epilogue: D row = (lane>>4)*4 + reg, col = lane&15  (verified C/D layout)
  #pragma unroll
  for (int fn = 0; fn < 2; ++fn) {
    int col = n0 + wn*32 + fn*16 + l15;
    float bv = bias[col];
    #pragma unroll
    for (int fm = 0; fm < 4; ++fm) {
      #pragma unroll
      for (int i = 0; i < 4; ++i) {
        int m = m0 + wm*64 + fm*16 + l4*4 + i;
        if (m >= M) continue;
        float v = acc[fm][fn][i] + bv;
        if (RELU) v = fmaxf(v, 0.f);
        C[(size_t)m * Nout + col] = (CT)v;
      }
    }
  }
}

static inline int cdiv(int x, int y) { return (x + y - 1) / y; }

extern "C" void kernel_launch(void* const* d_in, const int* in_sizes, int n_in,
                              void* d_out, int out_size, void* d_ws, size_t ws_size,
                              hipStream_t stream) {
  const float* feature  = (const float*)d_in[0];
  const float* W_msg    = (const float*)d_in[1];   // [4,256,256]
  const float* b_msg    = (const float*)d_in[2];   // [1024]
  const float* w_ih     = (const float*)d_in[3];
  const float* w_hh     = (const float*)d_in[4];
  const float* b_ih     = (const float*)d_in[5];
  const float* b_hh     = (const float*)d_in[6];
  const float* conv1_w  = (const float*)d_in[7];
  const float* conv1_b  = (const float*)d_in[8];
  const float* conv2_w  = (const float*)d_in[9];   // [256,256,1]
  const float* conv2_b  = (const float*)d_in[10];
  const float* convc1_w = (const float*)d_in[11];
  const float* convc1_b = (const float*)d_in[12];
  const float* convc2_w = (const float*)d_in[13];
  const float* convc2_b = (const float*)d_in[14];
  const float* mlpy_w   = (const float*)d_in[15];
  const float* mlpy_b   = (const float*)d_in[16];
  const float* mlpz_w   = (const float*)d_in[17];
  const float* mlpz_b   = (const float*)d_in[18];
  const int*   esrc     = (const int*)d_in[19];
  const int*   edst     = (const int*)d_in[20];
  const int*   etyp     = (const int*)d_in[21];
  float* out = (float*)d_out;

  // ---- workspace layout (bytes); peak ~128 MB ----
  char* base = (char*)d_ws;
  size_t off = 0;
  auto alloc = [&](size_t bytes) { void* p = base + off; off = (off + bytes + 255) & ~(size_t)255; return p; };
  float*    h      = (float*)   alloc((size_t)Ntot*OUTF*4);    // 16.8 MB
  _Float16* h16    = (_Float16*)alloc((size_t)Ntot*OUTF*2);    //  8.4 MB
  _Float16* Wext16 = (_Float16*)alloc((size_t)256*SK*2);       //  0.54 MB
  _Float16* wih16  = (_Float16*)alloc((size_t)768*256*2);
  _Float16* whh16  = (_Float16*)alloc((size_t)768*256*2);
  float*    bias0  = (float*)   alloc(256*4);                  // zeros
  int* rowptr = (int*)alloc((Ntot+1)*4);
  int* cnt    = (int*)alloc(Ntot*4);
  int* eidx   = (int*)alloc((size_t)Etot*4);
  char* big   = (char*)alloc((size_t)Ntot*1536*4);             // 100.9 MB shared region
  // GGNN phase views of big:
  //   gi  = big[0 : 50.4MB)      (f32, N*768)
  //   gh  = big[50.4 : 100.9MB)  (f32, N*768)
  //   s16 = big[50.4 : 85.1MB)   (f16, N*1056) — dead before gh-GEMM writes gh
  //   a16 = big[85.1 : 93.5MB)   (f16, N*256)  — consumed by gi-GEMM before gh written
  float*    gi  = (float*)big;
  float*    gh  = gi + (size_t)Ntot*768;
  _Float16* s16 = (_Float16*)(big + (size_t)Ntot*768*4);
  _Float16* a16 = s16 + (size_t)Ntot*SK;
  // conv phase views of big (GGNN scratch dead; 96.2MB data + 2.0MB weights <= 100.9MB)
  float*    Y2   = (float*)big;                              // 32*127*256 f32
  float*    Z2   = Y2 + (size_t)Bg*127*OUTF;                 // 32*127*384 f32
  float*    y1   = Z2 + (size_t)Bg*127*CATF;                 // 32*511*256 f32
  float*    y2   = y1 + (size_t)Bg*511*OUTF;                 // 32*255*256 f32
  _Float16* p1   = (_Float16*)(y2 + (size_t)Bg*255*OUTF);    // 32*255*256 f16
  _Float16* cb16 = p1 + (size_t)Bg*255*OUTF;                 // 16416*384 f16
  float*    z1   = (float*)(cb16 + (size_t)Ntot*CATF);       // 32*511*384 f32
  float*    z2   = z1 + (size_t)Bg*511*CATF;                 // 32*254*384 f32
  _Float16* pz1  = (_Float16*)(z2 + (size_t)Bg*254*CATF);    // 32*255*384 f16
  _Float16* wk1  = pz1 + (size_t)Bg*255*CATF;                // 256*768  f16 (conv-phase only)
  _Float16* wkc1 = wk1 + (size_t)256*768;                    // 384*1152 f16
  _Float16* wkc2 = wkc1 + (size_t)384*1152;                  // 384*768  f16
  _Float16* c2w16= wkc2 + (size_t)384*768;                   // 256*256  f16

  dim3 blk(256);

  // 1. h = pad(feature); weight conversions; zero bias
  pad_h_k<<<cdiv(Ntot*OUTF,256), blk, 0, stream>>>(feature, h, h16);
  repack_wext_k<<<cdiv(256*SK,256), blk, 0, stream>>>(W_msg, b_msg, Wext16);
  cvt_k<<<cdiv(768*256/4,256), blk, 0, stream>>>(w_ih, wih16, 768*256);
  cvt_k<<<cdiv(768*256/4,256), blk, 0, stream>>>(w_hh, whh16, 768*256);
  hipMemsetAsync(bias0, 0, 256*4, stream);

  // 2. CSR by dst
  zero_int_k<<<cdiv(Ntot,256), blk, 0, stream>>>(cnt, Ntot);
  hist_k<<<cdiv(Etot,256), blk, 0, stream>>>(edst, cnt);
  scan_k<<<1, blk, 0, stream>>>(cnt, rowptr);
  zero_int_k<<<cdiv(Ntot,256), blk, 0, stream>>>(cnt, Ntot);
  fill_k<<<cdiv(Etot,256), blk, 0, stream>>>(edst, rowptr, cnt, eidx);

  // 3. GGNN steps: gather-first aggregation, then a = s @ Wext^T (bias via K-ext)
  for (int s = 0; s < NSTEP; ++s) {
    gather_k<<<Ntot, blk, 0, stream>>>(h16, rowptr, eidx, esrc, etyp, s16);
    hgemm<_Float16,false,false><<<dim3(cdiv(Ntot,128), 4), blk, 0, stream>>>(
        s16, Wext16, bias0, a16, Ntot, 256, SK, SK, 0, 0);
    hgemm<float,false,false><<<dim3(cdiv(Ntot,128), 12), blk, 0, stream>>>(
        a16, wih16, b_ih, gi, Ntot, 768, 256, 256, 0, 0);
    hgemm<float,false,false><<<dim3(cdiv(Ntot,128), 12), blk, 0, stream>>>(
        h16, whh16, b_hh, gh, Ntot, 768, 256, 256, 0, 0);
    gru_gate_k<<<cdiv(Ntot*OUTF,256), blk, 0, stream>>>(gi, gh, h, h16);
  }

  // 4. conv-head weight repacks (conv-phase spare of big)
  repack16_k<<<cdiv(256*256*3,256), blk, 0, stream>>>(conv1_w,  wk1,  256, 256, 3);
  repack16_k<<<cdiv(384*384*3,256), blk, 0, stream>>>(convc1_w, wkc1, 384, 384, 3);
  repack16_k<<<cdiv(384*384*2,256), blk, 0, stream>>>(convc2_w, wkc2, 384, 384, 2);
  cvt_k<<<cdiv(256*256/4,256), blk, 0, stream>>>(conv2_w, c2w16, 256*256);

  // 5. Y head: conv1(K=3) -> pool3 -> conv2(K=1) -> pool2
  hgemm<float,true,true><<<dim3(cdiv(Bg*511,128), 4), blk, 0, stream>>>(
      h16, wk1, conv1_b, y1, Bg*511, 256, 768, 256, 511, NNg);
  maxpool_k<_Float16><<<cdiv(Bg*255*256,256), blk, 0, stream>>>(y1, p1, 511, 255, 256, 3);
  hgemm<float,true,false><<<dim3(cdiv(Bg*255,128), 4), blk, 0, stream>>>(
      p1, c2w16, conv2_b, y2, Bg*255, 256, 256, 256, 0, 0);
  maxpool_k<float><<<cdiv(Bg*127*256,256), blk, 0, stream>>>(y2, Y2, 255, 127, 256, 2);

  // 6. Z head: cb16=concat(h16,(f16)feature); convc1(K=3) -> pool3 -> convc2(K=2) -> pool2
  build_cb16_k<<<cdiv(Ntot*CATF,256), blk, 0, stream>>>(h16, feature, cb16);
  hgemm<float,true,true><<<dim3(cdiv(Bg*511,128), 6), blk, 0, stream>>>(
      cb16, wkc1, convc1_b, z1, Bg*511, 384, 1152, 384, 511, NNg);
  maxpool_k<_Float16><<<cdiv(Bg*255*384,256), blk, 0, stream>>>(z1, pz1, 511, 255, 384, 3);
  hgemm<float,true,true><<<dim3(cdiv(Bg*254,128), 6), blk, 0, stream>>>(
      pz1, wkc2, convc2_b, z2, Bg*254, 384, 768, 384, 254, 255);
  maxpool_k<float><<<cdiv(Bg*127*384,256), blk, 0, stream>>>(z2, Z2, 254, 127, 384, 2);

  // 7. head
  head_k<<<Bg, 128, 0, stream>>>(Y2, Z2, mlpy_w, mlpy_b, mlpz_w, mlpz_b, out);
}

// Round 11
// 896.791 us; speedup vs baseline: 2.7981x; 1.0845x over previous
//
#include <hip/hip_runtime.h>

#define Bg    32
#define NNg   513
#define INF   128
#define OUTF  256
#define TT    4
#define NSTEP 4
#define DEGg  16
#define Ntot  (Bg*NNg)        // 16416
#define Etot  (Ntot*DEGg)     // 262656
#define CATF  (OUTF+INF)      // 384
#define SK    1056            // 1024 + 4 cnt + 28 pad
#define NSB   65              // scan blocks: cdiv(16416,256)

typedef _Float16 h8_t __attribute__((ext_vector_type(8)));
typedef float    f4_t __attribute__((ext_vector_type(4)));

// ---------------- elementwise ----------------
__global__ void pad_h_k(const float* __restrict__ feat, float* __restrict__ h,
                        _Float16* __restrict__ h16) {
  int idx = blockIdx.x*256 + threadIdx.x;
  if (idx >= Ntot*OUTF) return;
  int n = idx >> 8, c = idx & 255;
  float v = (c < INF) ? feat[n*INF + c] : 0.f;
  h[idx] = v;
  h16[idx] = (_Float16)v;
}

__global__ void cvt_k(const float* __restrict__ s, _Float16* __restrict__ d, int n) {
  int i = (blockIdx.x*256 + threadIdx.x) * 4;
  if (i >= n) return;
  float4 v = *reinterpret_cast<const float4*>(s + i);
  _Float16 o[4] = {(_Float16)v.x, (_Float16)v.y, (_Float16)v.z, (_Float16)v.w};
  *reinterpret_cast<ushort4*>(d + i) = *reinterpret_cast<ushort4*>(o);
}

// cb16[n][c] = c<256 ? h16[n][c] : (f16)feature[n][c-256]
__global__ void build_cb16_k(const _Float16* __restrict__ h16,
                             const float* __restrict__ feat,
                             _Float16* __restrict__ cb) {
  int idx = blockIdx.x*256 + threadIdx.x;
  if (idx >= Ntot*CATF) return;
  int n = idx / CATF, c = idx % CATF;
  cb[idx] = (c < OUTF) ? h16[n*OUTF + c] : (_Float16)feat[n*INF + (c - OUTF)];
}

__global__ void zero_int_k(int* __restrict__ p, int n) {
  int i = blockIdx.x*256 + threadIdx.x;
  if (i < n) p[i] = 0;
}

__global__ void hist_k(const int* __restrict__ dst, int* __restrict__ cnt) {
  int e = blockIdx.x*256 + threadIdx.x;
  if (e < Etot) atomicAdd(&cnt[dst[e]], 1);
}

// ---- 3-phase parallel exclusive scan of cnt[Ntot] -> rowptr ----
__global__ void scan1_k(const int* __restrict__ cnt, int* __restrict__ rowptr,
                        int* __restrict__ bsum) {
  __shared__ int buf[256];
  int t = threadIdx.x;
  int i = blockIdx.x*256 + t;
  int v = (i < Ntot) ? cnt[i] : 0;
  buf[t] = v;
  __syncthreads();
  #pragma unroll
  for (int off = 1; off < 256; off <<= 1) {
    int x = (t >= off) ? buf[t - off] : 0;
    __syncthreads();
    buf[t] += x;
    __syncthreads();
  }
  if (i < Ntot) rowptr[i] = buf[t] - v;   // exclusive within block
  if (t == 255) bsum[blockIdx.x] = buf[255];
}

__global__ void scan2_k(int* __restrict__ bsum) {   // single block; NSB <= 256
  __shared__ int buf[256];
  int t = threadIdx.x;
  int v = (t < NSB) ? bsum[t] : 0;
  buf[t] = v;
  __syncthreads();
  #pragma unroll
  for (int off = 1; off < 256; off <<= 1) {
    int x = (t >= off) ? buf[t - off] : 0;
    __syncthreads();
    buf[t] += x;
    __syncthreads();
  }
  if (t < NSB) bsum[t] = buf[t] - v;      // exclusive block offsets
}

__global__ void scan3_k(int* __restrict__ rowptr, const int* __restrict__ bsum) {
  int i = blockIdx.x*256 + threadIdx.x;
  if (i < Ntot) rowptr[i] += bsum[blockIdx.x];
  if (i == 0) rowptr[Ntot] = Etot;
}

__global__ void fill_k(const int* __restrict__ dst, const int* __restrict__ rowptr,
                       int* __restrict__ cursor, int* __restrict__ eidx) {
  int e = blockIdx.x*256 + threadIdx.x;
  if (e < Etot) {
    int d = dst[e];
    int pos = atomicAdd(&cursor[d], 1);
    eidx[rowptr[d] + pos] = e;
  }
}

// Per-type neighbor sums: s16[n][t*256+c] = sum_{e: dst=n, type=t} h16[src(e)][c]
// plus s16[n][1024+t] = count of type-t in-edges (for exact b_msg handling), pad zeros.
__global__ void gather_k(const _Float16* __restrict__ h16, const int* __restrict__ rowptr,
                         const int* __restrict__ eidx, const int* __restrict__ esrc,
                         const int* __restrict__ etyp, _Float16* __restrict__ s16) {
  __shared__ int src_s[128];
  __shared__ int typ_s[128];
  int n = blockIdx.x;
  int c = threadIdx.x;  // 256
  int s0 = rowptr[n], e0 = rowptr[n+1];
  float a0 = 0.f, a1 = 0.f, a2 = 0.f, a3 = 0.f;
  int c0 = 0, c1 = 0, c2 = 0, c3 = 0;
  for (int base = s0; base < e0; base += 128) {
    int m = e0 - base; if (m > 128) m = 128;
    if (c < m) {
      int ee = eidx[base + c];
      src_s[c] = esrc[ee];
      typ_s[c] = etyp[ee];
    }
    __syncthreads();
    for (int i = 0; i < m; ++i) {
      int t = typ_s[i];
      float v = (float)h16[(size_t)src_s[i]*256 + c];
      a0 += (t == 0) ? v : 0.f;
      a1 += (t == 1) ? v : 0.f;
      a2 += (t == 2) ? v : 0.f;
      a3 += (t == 3) ? v : 0.f;
      c0 += (t == 0); c1 += (t == 1); c2 += (t == 2); c3 += (t == 3);
    }
    __syncthreads();
  }
  size_t b = (size_t)n * SK;
  s16[b + 0*256 + c] = (_Float16)a0;
  s16[b + 1*256 + c] = (_Float16)a1;
  s16[b + 2*256 + c] = (_Float16)a2;
  s16[b + 3*256 + c] = (_Float16)a3;
  if (c < 32) {
    float cv = (c == 0) ? (float)c0 : (c == 1) ? (float)c1 :
               (c == 2) ? (float)c2 : (c == 3) ? (float)c3 : 0.f;
    s16[b + 1024 + c] = (_Float16)cv;
  }
}

// Wext[co][k]: k<1024 -> W_msg[k>>8][co][k&255]; k in [1024,1028) -> b_msg[(k-1024)*256+co]; else 0
__global__ void repack_wext_k(const float* __restrict__ Wmsg, const float* __restrict__ bmsg,
                              _Float16* __restrict__ wext) {
  int idx = blockIdx.x*256 + threadIdx.x;
  if (idx >= 256*SK) return;
  int co = idx / SK, k = idx % SK;
  float v;
  if (k < 1024)      { int t = k >> 8, ci = k & 255; v = Wmsg[((size_t)t*256 + co)*256 + ci]; }
  else if (k < 1028) { v = bmsg[(k - 1024)*256 + co]; }
  else               { v = 0.f; }
  wext[idx] = (_Float16)v;
}

__global__ void gru_gate_k(const float* __restrict__ gi, const float* __restrict__ gh,
                           float* __restrict__ h, _Float16* __restrict__ h16) {
  int idx = blockIdx.x*256 + threadIdx.x;
  if (idx >= Ntot*OUTF) return;
  int n = idx >> 8, g = idx & 255;
  const float* gin = gi + (size_t)n*768;
  const float* ghn = gh + (size_t)n*768;
  float r  = 1.f / (1.f + expf(-(gin[g]       + ghn[g])));
  float z  = 1.f / (1.f + expf(-(gin[256 + g] + ghn[256 + g])));
  float nn = tanhf(gin[512 + g] + r * ghn[512 + g]);
  float hv = h[idx];
  float o = (1.f - z) * nn + z * hv;
  h[idx] = o;
  h16[idx] = (_Float16)o;
}

template<typename OT>
__global__ void maxpool_k(const float* __restrict__ in, OT* __restrict__ out,
                          int Lin, int Lp, int C, int kwin) {
  int idx = blockIdx.x*256 + threadIdx.x;
  int total = Bg*Lp*C;
  if (idx >= total) return;
  int c = idx % C; int r = idx / C; int p = r % Lp; int b = r / Lp;
  const float* base = in + ((size_t)(b*Lin + 2*p))*C + c;
  float v = base[0];
  for (int w = 1; w < kwin; ++w) v = fmaxf(v, base[(size_t)w*C]);
  out[idx] = (OT)v;
}

// wk16[co][k][ci] = (f16) w[co][ci][k]
__global__ void repack16_k(const float* __restrict__ w, _Float16* __restrict__ wk,
                           int Cout, int Cin, int K) {
  int idx = blockIdx.x*256 + threadIdx.x;
  int total = Cout*Cin*K;
  if (idx >= total) return;
  int ci = idx % Cin; int r = idx / Cin; int k = r % K; int co = r / K;
  wk[idx] = (_Float16)w[(co*Cin + ci)*K + k];
}

__global__ void head_k(const float* __restrict__ Y2, const float* __restrict__ Z2,
                       const float* __restrict__ wy, const float* __restrict__ by,
                       const float* __restrict__ wz, const float* __restrict__ bz,
                       float* __restrict__ out) {
  int b = blockIdx.x;
  int tid = threadIdx.x;  // 128
  __shared__ float red[128];
  float sum = 0.f;
  for (int p = tid; p < 127; p += 128) {
    const float* yr = Y2 + ((size_t)(b*127 + p))*OUTF;
    const float* zr = Z2 + ((size_t)(b*127 + p))*CATF;
    float yv = by[0], zv = bz[0];
    for (int c = 0; c < OUTF; ++c) yv = fmaf(yr[c], wy[c], yv);
    for (int c = 0; c < CATF; ++c) zv = fmaf(zr[c], wz[c], zv);
    sum += yv * zv;
  }
  red[tid] = sum;
  __syncthreads();
  for (int off = 64; off > 0; off >>= 1) {
    if (tid < off) red[tid] += red[tid + off];
    __syncthreads();
  }
  if (tid == 0) out[b] = 1.f / (1.f + expf(-red[0] / 127.f));
}

// ------------- f16 MFMA GEMM: C[m][n] = act(sum_k A[m][k]*W[n][k] + bias[n]) -------------
// Tile 128x128xK, BK=32, 256 threads = 4 waves (2x2), wave tile 64x64 = 4x4 MFMA frags.
// Staging: each thread loads 2x int4 (16 f16) for A AND for W -> full 128x32 tiles.
// A row m at A + node(m)*arstride (f16 elems), K contiguous. CT = output type (float/f16).
// N must be a multiple of 128. MAPPED: node(m) = (m/Lout)*NNodes + (m%Lout).
template<typename CT, bool RELU, bool MAPPED>
__global__ __launch_bounds__(256, 2) void hgemm(
    const _Float16* __restrict__ A, const _Float16* __restrict__ W,
    const float* __restrict__ bias, CT* __restrict__ C,
    int M, int Nout, int K, int arstride, int Lout, int NNodes) {
  __shared__ _Float16 As[128][40];   // padded: 80B row stride -> <=2-way bank aliasing (free)
  __shared__ _Float16 Ws[128][40];
  int tid = threadIdx.x;
  int lane = tid & 63, wid = tid >> 6;
  int wm = wid >> 1, wn = wid & 1;
  int l15 = lane & 15, l4 = lane >> 4;
  int m0 = blockIdx.x * 128, n0 = blockIdx.y * 128;

  // staging: A/W each 128 rows x 32 f16; 2 threads/row x 16 f16 (2x int4) per tile
  int s_row = tid >> 1;
  int s_col = (tid & 1) * 16;
  int m_s = m0 + s_row;
  bool a_ok = (m_s < M);
  int mc = a_ok ? m_s : (M - 1);
  int node = MAPPED ? (mc / Lout) * NNodes + (mc % Lout) : mc;
  const _Float16* a_src = A + (size_t)node * arstride + s_col;
  const _Float16* w_src = W + (size_t)(n0 + s_row) * K + s_col;

  f4_t acc[4][4] = {};

  for (int k0 = 0; k0 < K; k0 += 32) {
    if (k0) __syncthreads();
    int4 va0 = {0,0,0,0}, va1 = {0,0,0,0};
    if (a_ok) {
      const int4* ga = reinterpret_cast<const int4*>(a_src + k0);
      va0 = ga[0]; va1 = ga[1];
    }
    const int4* gw = reinterpret_cast<const int4*>(w_src + k0);
    int4 vw0 = gw[0], vw1 = gw[1];
    *reinterpret_cast<int4*>(&As[s_row][s_col])     = va0;
    *reinterpret_cast<int4*>(&As[s_row][s_col + 8]) = va1;
    *reinterpret_cast<int4*>(&Ws[s_row][s_col])     = vw0;
    *reinterpret_cast<int4*>(&Ws[s_row][s_col + 8]) = vw1;
    __syncthreads();

    h8_t af[4], bf[4];
    #pragma unroll
    for (int fm = 0; fm < 4; ++fm)
      af[fm] = *reinterpret_cast<const h8_t*>(&As[wm*64 + fm*16 + l15][l4*8]);
    #pragma unroll
    for (int fn = 0; fn < 4; ++fn)
      bf[fn] = *reinterpret_cast<const h8_t*>(&Ws[wn*64 + fn*16 + l15][l4*8]);
    #pragma unroll
    for (int fm = 0; fm < 4; ++fm)
      #pragma unroll
      for (int fn = 0; fn < 4; ++fn)
        acc[fm][fn] = __builtin_amdgcn_mfma_f32_16x16x32_f16(af[fm], bf[fn], acc[fm][fn], 0, 0, 0);
  }

  // epilogue: D row = (lane>>4)*4 + reg, col = lane&15  (verified C/D layout)
  #pragma unroll
  for (int fn = 0; fn < 4; ++fn) {
    int col = n0 + wn*64 + fn*16 + l15;
    float bv = bias[col];
    #pragma unroll
    for (int fm = 0; fm < 4; ++fm) {
      #pragma unroll
      for (int i = 0; i < 4; ++i) {
        int m = m0 + wm*64 + fm*16 + l4*4 + i;
        if (m >= M) continue;
        float v = acc[fm][fn][i] + bv;
        if (RELU) v = fmaxf(v, 0.f);
        C[(size_t)m * Nout + col] = (CT)v;
      }
    }
  }
}

static inline int cdiv(int x, int y) { return (x + y - 1) / y; }

extern "C" void kernel_launch(void* const* d_in, const int* in_sizes, int n_in,
                              void* d_out, int out_size, void* d_ws, size_t ws_size,
                              hipStream_t stream) {
  const float* feature  = (const float*)d_in[0];
  const float* W_msg    = (const float*)d_in[1];   // [4,256,256]
  const float* b_msg    = (const float*)d_in[2];   // [1024]
  const float* w_ih     = (const float*)d_in[3];
  const float* w_hh     = (const float*)d_in[4];
  const float* b_ih     = (const float*)d_in[5];
  const float* b_hh     = (const float*)d_in[6];
  const float* conv1_w  = (const float*)d_in[7];
  const float* conv1_b  = (const float*)d_in[8];
  const float* conv2_w  = (const float*)d_in[9];   // [256,256,1]
  const float* conv2_b  = (const float*)d_in[10];
  const float* convc1_w = (const float*)d_in[11];
  const float* convc1_b = (const float*)d_in[12];
  const float* convc2_w = (const float*)d_in[13];
  const float* convc2_b = (const float*)d_in[14];
  const float* mlpy_w   = (const float*)d_in[15];
  const float* mlpy_b   = (const float*)d_in[16];
  const float* mlpz_w   = (const float*)d_in[17];
  const float* mlpz_b   = (const float*)d_in[18];
  const int*   esrc     = (const int*)d_in[19];
  const int*   edst     = (const int*)d_in[20];
  const int*   etyp     = (const int*)d_in[21];
  float* out = (float*)d_out;

  // ---- workspace layout (bytes); peak ~128 MB ----
  char* base = (char*)d_ws;
  size_t off = 0;
  auto alloc = [&](size_t bytes) { void* p = base + off; off = (off + bytes + 255) & ~(size_t)255; return p; };
  float*    h      = (float*)   alloc((size_t)Ntot*OUTF*4);    // 16.8 MB
  _Float16* h16    = (_Float16*)alloc((size_t)Ntot*OUTF*2);    //  8.4 MB
  _Float16* Wext16 = (_Float16*)alloc((size_t)256*SK*2);       //  0.54 MB
  _Float16* wih16  = (_Float16*)alloc((size_t)768*256*2);
  _Float16* whh16  = (_Float16*)alloc((size_t)768*256*2);
  float*    bias0  = (float*)   alloc(256*4);                  // zeros
  int* rowptr = (int*)alloc((Ntot+1)*4);
  int* cnt    = (int*)alloc(Ntot*4);
  int* bsum   = (int*)alloc(NSB*4);
  int* eidx   = (int*)alloc((size_t)Etot*4);
  char* big   = (char*)alloc((size_t)Ntot*1536*4);             // 100.9 MB shared region
  // GGNN phase views of big:
  //   gi  = big[0 : 50.4MB)      (f32, N*768)
  //   gh  = big[50.4 : 100.9MB)  (f32, N*768)
  //   s16 = big[50.4 : 85.1MB)   (f16, N*1056) — dead before gh-GEMM writes gh
  //   a16 = big[85.1 : 93.5MB)   (f16, N*256)  — consumed by gi-GEMM before gh written
  float*    gi  = (float*)big;
  float*    gh  = gi + (size_t)Ntot*768;
  _Float16* s16 = (_Float16*)(big + (size_t)Ntot*768*4);
  _Float16* a16 = s16 + (size_t)Ntot*SK;
  // conv phase views of big (GGNN scratch dead; 96.2MB data + 2.0MB weights <= 100.9MB)
  float*    Y2   = (float*)big;                              // 32*127*256 f32
  float*    Z2   = Y2 + (size_t)Bg*127*OUTF;                 // 32*127*384 f32
  float*    y1   = Z2 + (size_t)Bg*127*CATF;                 // 32*511*256 f32
  float*    y2   = y1 + (size_t)Bg*511*OUTF;                 // 32*255*256 f32
  _Float16* p1   = (_Float16*)(y2 + (size_t)Bg*255*OUTF);    // 32*255*256 f16
  _Float16* cb16 = p1 + (size_t)Bg*255*OUTF;                 // 16416*384 f16
  float*    z1   = (float*)(cb16 + (size_t)Ntot*CATF);       // 32*511*384 f32
  float*    z2   = z1 + (size_t)Bg*511*CATF;                 // 32*254*384 f32
  _Float16* pz1  = (_Float16*)(z2 + (size_t)Bg*254*CATF);    // 32*255*384 f16
  _Float16* wk1  = pz1 + (size_t)Bg*255*CATF;                // 256*768  f16 (conv-phase only)
  _Float16* wkc1 = wk1 + (size_t)256*768;                    // 384*1152 f16
  _Float16* wkc2 = wkc1 + (size_t)384*1152;                  // 384*768  f16
  _Float16* c2w16= wkc2 + (size_t)384*768;                   // 256*256  f16

  dim3 blk(256);

  // 1. h = pad(feature); weight conversions; zero bias
  pad_h_k<<<cdiv(Ntot*OUTF,256), blk, 0, stream>>>(feature, h, h16);
  repack_wext_k<<<cdiv(256*SK,256), blk, 0, stream>>>(W_msg, b_msg, Wext16);
  cvt_k<<<cdiv(768*256/4,256), blk, 0, stream>>>(w_ih, wih16, 768*256);
  cvt_k<<<cdiv(768*256/4,256), blk, 0, stream>>>(w_hh, whh16, 768*256);
  hipMemsetAsync(bias0, 0, 256*4, stream);

  // 2. CSR by dst (parallel 3-phase scan)
  zero_int_k<<<cdiv(Ntot,256), blk, 0, stream>>>(cnt, Ntot);
  hist_k<<<cdiv(Etot,256), blk, 0, stream>>>(edst, cnt);
  scan1_k<<<NSB, blk, 0, stream>>>(cnt, rowptr, bsum);
  scan2_k<<<1, blk, 0, stream>>>(bsum);
  scan3_k<<<NSB, blk, 0, stream>>>(rowptr, bsum);
  zero_int_k<<<cdiv(Ntot,256), blk, 0, stream>>>(cnt, Ntot);
  fill_k<<<cdiv(Etot,256), blk, 0, stream>>>(edst, rowptr, cnt, eidx);

  // 3. GGNN steps: gather-first aggregation, then a = s @ Wext^T (bias via K-ext)
  for (int s = 0; s < NSTEP; ++s) {
    gather_k<<<Ntot, blk, 0, stream>>>(h16, rowptr, eidx, esrc, etyp, s16);
    hgemm<_Float16,false,false><<<dim3(cdiv(Ntot,128), 2), blk, 0, stream>>>(
        s16, Wext16, bias0, a16, Ntot, 256, SK, SK, 0, 0);
    hgemm<float,false,false><<<dim3(cdiv(Ntot,128), 6), blk, 0, stream>>>(
        a16, wih16, b_ih, gi, Ntot, 768, 256, 256, 0, 0);
    hgemm<float,false,false><<<dim3(cdiv(Ntot,128), 6), blk, 0, stream>>>(
        h16, whh16, b_hh, gh, Ntot, 768, 256, 256, 0, 0);
    gru_gate_k<<<cdiv(Ntot*OUTF,256), blk, 0, stream>>>(gi, gh, h, h16);
  }

  // 4. conv-head weight repacks (conv-phase spare of big)
  repack16_k<<<cdiv(256*256*3,256), blk, 0, stream>>>(conv1_w,  wk1,  256, 256, 3);
  repack16_k<<<cdiv(384*384*3,256), blk, 0, stream>>>(convc1_w, wkc1, 384, 384, 3);
  repack16_k<<<cdiv(384*384*2,256), blk, 0, stream>>>(convc2_w, wkc2, 384, 384, 2);
  cvt_k<<<cdiv(256*256/4,256), blk, 0, stream>>>(conv2_w, c2w16, 256*256);

  // 5. Y head: conv1(K=3) -> pool3 -> conv2(K=1) -> pool2
  hgemm<float,true,true><<<dim3(cdiv(Bg*511,128), 2), blk, 0, stream>>>(
      h16, wk1, conv1_b, y1, Bg*511, 256, 768, 256, 511, NNg);
  maxpool_k<_Float16><<<cdiv(Bg*255*256,256), blk, 0, stream>>>(y1, p1, 511, 255, 256, 3);
  hgemm<float,true,false><<<dim3(cdiv(Bg*255,128), 2), blk, 0, stream>>>(
      p1, c2w16, conv2_b, y2, Bg*255, 256, 256, 256, 0, 0);
  maxpool_k<float><<<cdiv(Bg*127*256,256), blk, 0, stream>>>(y2, Y2, 255, 127, 256, 2);

  // 6. Z head: cb16=concat(h16,(f16)feature); convc1(K=3) -> pool3 -> convc2(K=2) -> pool2
  build_cb16_k<<<cdiv(Ntot*CATF,256), blk, 0, stream>>>(h16, feature, cb16);
  hgemm<float,true,true><<<dim3(cdiv(Bg*511,128), 3), blk, 0, stream>>>(
      cb16, wkc1, convc1_b, z1, Bg*511, 384, 1152, 384, 511, NNg);
  maxpool_k<_Float16><<<cdiv(Bg*255*384,256), blk, 0, stream>>>(z1, pz1, 511, 255, 384, 3);
  hgemm<float,true,true><<<dim3(cdiv(Bg*254,128), 3), blk, 0, stream>>>(
      pz1, wkc2, convc2_b, z2, Bg*254, 384, 768, 384, 254, 255);
  maxpool_k<float><<<cdiv(Bg*127*384,256), blk, 0, stream>>>(z2, Z2, 254, 127, 384, 2);

  // 7. head
  head_k<<<Bg, 128, 0, stream>>>(Y2, Z2, mlpy_w, mlpy_b, mlpz_w, mlpz_b, out);
}